// Round 3
// baseline (208.347 us; speedup 1.0000x reference)
//
#include <hip/hip_runtime.h>

#define N_NODES 50000
#define N_EDGES 800000
#define IN_CH 64
#define HIDDEN 128
#define OUT_CH 64
#define CAP 64      // bucket capacity/node (Binomial(800K,1/50K): P(deg>=64)~2e-18)
#define BINS 196    // nodes/bin = 256
#define CHUNK 3125  // edges per binA block (256 blocks)
#define LCAP 48     // LDS per-bin capacity in binA
#define SEGCAP 4608 // per-bin segment capacity

typedef unsigned short ushort_t;
typedef unsigned int uint_t;
typedef __attribute__((ext_vector_type(8))) short short8;
typedef __attribute__((ext_vector_type(4))) float f32x4;

__device__ __forceinline__ float bits2f(unsigned int u16) {
    union { unsigned int i; float f; } v;
    v.i = (u16 & 0xFFFFu) << 16;
    return v.f;
}

__device__ __forceinline__ ushort_t f2bits(float f) {
    union { float f; unsigned int i; } v;
    v.f = f;
    unsigned int x = v.i;
    if ((x & 0x7F800000u) == 0x7F800000u) return (ushort_t)(x >> 16); // inf/nan
    unsigned int r = (x + 0x7FFFu + ((x >> 16) & 1u)) >> 16;          // RNE
    return (ushort_t)r;
}

__device__ __forceinline__ uint_t pack2(float x, float y) {
    return (uint_t)f2bits(x) | ((uint_t)f2bits(y) << 16);
}

// ===== merged pass: binA (blocks 0..255) + weight pack (256..447) + x cvt ==
__global__ __launch_bounds__(256) void binA_prep(const int* __restrict__ ei,
                                                 int* __restrict__ gcur,
                                                 uint_t* __restrict__ seg,
                                                 const float* __restrict__ x,
                                                 uint_t* __restrict__ xu,
                                                 const float* __restrict__ W1, ushort_t* __restrict__ pW1,
                                                 const float* __restrict__ W2, ushort_t* __restrict__ pW2,
                                                 const float* __restrict__ W3, ushort_t* __restrict__ pW3,
                                                 const float* __restrict__ W4, ushort_t* __restrict__ pW4) {
    __shared__ uint_t lbin[BINS][LCAP];   // 37.6 KB (allocated for all blocks)
    __shared__ int lcnt[BINS];
    __shared__ int lbase[BINS];
    int blk = blockIdx.x;
    int t = threadIdx.x;
    if (blk < 256) {
        // ---------------- binA: LDS-binned edge partition ----------------
        for (int i = t; i < BINS; i += 256) lcnt[i] = 0;
        __syncthreads();
        int e0 = blk * CHUNK;
        int e1 = e0 + CHUNK; if (e1 > N_EDGES) e1 = N_EDGES;
        for (int e = e0 + t; e < e1; e += 256) {
            int src = ei[e];
            int dst = ei[N_EDGES + e];
            int bin = dst >> 8;
            uint_t rec = ((uint_t)src << 16) | (uint_t)(dst & 255);
            int pos = atomicAdd(&lcnt[bin], 1);
            if (pos < LCAP) {
                lbin[bin][pos] = rec;
            } else {
                int gp = atomicAdd(&gcur[bin], 1);
                if (gp < SEGCAP) seg[(size_t)bin * SEGCAP + gp] = rec;
            }
        }
        __syncthreads();
        for (int i = t; i < BINS; i += 256) {
            int c = lcnt[i]; if (c > LCAP) c = LCAP;
            lbase[i] = atomicAdd(&gcur[i], c);
        }
        __syncthreads();
        int wv = t >> 6, ln = t & 63;
        for (int i = wv; i < BINS; i += 4) {
            int c = lcnt[i]; if (c > LCAP) c = LCAP;
            int base = lbase[i];
            for (int j = ln; j < c; j += 64)
                seg[(size_t)i * SEGCAP + base + j] = lbin[i][j];
        }
    } else if (blk < 448) {
        // ---------------- weight pack (fragment order, bf16) -------------
        int b = blk - 256;
        const float* W; ushort_t* o; int K, C, b0;
        if (b < 32)       { W = W1; o = pW1; K = IN_CH;  C = HIDDEN; b0 = 0; }
        else if (b < 96)  { W = W2; o = pW2; K = HIDDEN; C = HIDDEN; b0 = 32; }
        else if (b < 160) { W = W3; o = pW3; K = HIDDEN; C = HIDDEN; b0 = 96; }
        else              { W = W4; o = pW4; K = HIDDEN; C = OUT_CH; b0 = 160; }
        int tid = (b - b0) * 256 + t;
        int j = tid & 7;
        int l = (tid >> 3) & 63;
        int rest = tid >> 9;
        int KC = K >> 5;
        int kc = rest % KC;
        int nt = rest / KC;
        int k = kc * 32 + (l >> 4) * 8 + j;
        int n = nt * 16 + (l & 15);
        o[tid] = f2bits(W[(size_t)k * C + n]);
    } else {
        // ---------------- x -> bf16 convert ------------------------------
        int i = (blk - 448) * 256 + t;
        if (i < N_NODES * IN_CH / 2) {
            float2 v = ((const float2*)x)[i];
            xu[i] = pack2(v.x, v.y);
        }
    }
}

// ============== CSR pass B: per-bin bucket build, coalesced writes =========
__global__ __launch_bounds__(256) void binB(const uint_t* __restrict__ seg,
                                            const int* __restrict__ gcur,
                                            int* __restrict__ cnt,
                                            ushort_t* __restrict__ bucket) {
    __shared__ ushort_t lb[256 * CAP];    // 32 KB
    __shared__ int lc[256];
    int b = blockIdx.x;
    int t = threadIdx.x;
    lc[t] = 0;
    __syncthreads();
    int c = gcur[b]; if (c > SEGCAP) c = SEGCAP;
    const uint_t* s = seg + (size_t)b * SEGCAP;
    for (int i = t; i < c; i += 256) {
        uint_t rec = s[i];
        int ldst = rec & 255;
        int pos = atomicAdd(&lc[ldst], 1);
        if (pos < CAP) lb[ldst * CAP + pos] = (ushort_t)(rec >> 16);
    }
    __syncthreads();
    int n0 = b * 256;
    int nvalid = N_NODES - n0; if (nvalid > 256) nvalid = 256;
    uint4* gb = (uint4*)(bucket + (size_t)n0 * CAP);
    const uint4* lbv = (const uint4*)lb;
    int total = nvalid * (CAP / 8);
    for (int i = t; i < total; i += 256) gb[i] = lbv[i];
    if (t < nvalid) cnt[n0 + t] = lc[t];
}

// ======================= fused layer kernels =======================
// mfma_f32_16x16x32_bf16 layouts (m89/m91/m120-verified):
//   A: lane l holds A[m=l&15][k=(l>>4)*8+j];  B: lane l holds B[k=(l>>4)*8+j][n=l&15]
//   D: lane l, reg r holds D[(l>>4)*4+r][l&15]
#define TPAD 136   // LDS row stride in ushorts (= 68 words; stride-68 is 2-way max)

// layer1 = gather1 (into LDS) + mlp1.  64 nodes/block, 256 threads.
__global__ __launch_bounds__(256) void layer1(const uint_t* __restrict__ xu,
                                              const int* __restrict__ cnt,
                                              const ushort_t* __restrict__ bucket,
                                              const float* __restrict__ eps1,
                                              const ushort_t* __restrict__ pW1,
                                              const float* __restrict__ b1,
                                              const ushort_t* __restrict__ pW2,
                                              const float* __restrict__ b2,
                                              ushort_t* __restrict__ h1) {
    __shared__ __align__(16) ushort_t t[64][TPAD];   // 17.4 KB, reused agg -> inter-MLP tile
    int tid = threadIdx.x;
    int m0 = blockIdx.x * 64;
    // ---- gather phase: 8 groups x 32 lanes; group g does nodes m0+g*8+j ----
    int g = tid >> 5, li = tid & 31;
    float se = 1.0f + eps1[0];
    for (int j = 0; j < 8; j++) {
        int n = m0 + g * 8 + j;
        float r0 = 0.f, r1 = 0.f;
        if (n < N_NODES) {
            uint_t v = xu[(size_t)n * 32 + li];
            float s0 = se * bits2f(v), s1 = se * bits2f(v >> 16);
            float A0 = 0.f, A1 = 0.f, B0 = 0.f, B1 = 0.f, C0 = 0.f, C1 = 0.f, D0 = 0.f, D1 = 0.f;
            float E0 = 0.f, E1 = 0.f, F0 = 0.f, F1 = 0.f, G0 = 0.f, G1 = 0.f, H0 = 0.f, H1 = 0.f;
            int cn = cnt[n]; if (cn > CAP) cn = CAP;
            const ushort_t* bk = bucket + (size_t)n * CAP;
            int i = 0;
            for (; i + 7 < cn; i += 8) {
                uint4 p = *(const uint4*)(bk + i);
                uint_t u0 = xu[(size_t)(p.x & 0xFFFFu) * 32 + li];
                uint_t u1 = xu[(size_t)(p.x >> 16) * 32 + li];
                uint_t u2 = xu[(size_t)(p.y & 0xFFFFu) * 32 + li];
                uint_t u3 = xu[(size_t)(p.y >> 16) * 32 + li];
                uint_t u4 = xu[(size_t)(p.z & 0xFFFFu) * 32 + li];
                uint_t u5 = xu[(size_t)(p.z >> 16) * 32 + li];
                uint_t u6 = xu[(size_t)(p.w & 0xFFFFu) * 32 + li];
                uint_t u7 = xu[(size_t)(p.w >> 16) * 32 + li];
                A0 += bits2f(u0); A1 += bits2f(u0 >> 16);
                B0 += bits2f(u1); B1 += bits2f(u1 >> 16);
                C0 += bits2f(u2); C1 += bits2f(u2 >> 16);
                D0 += bits2f(u3); D1 += bits2f(u3 >> 16);
                E0 += bits2f(u4); E1 += bits2f(u4 >> 16);
                F0 += bits2f(u5); F1 += bits2f(u5 >> 16);
                G0 += bits2f(u6); G1 += bits2f(u6 >> 16);
                H0 += bits2f(u7); H1 += bits2f(u7 >> 16);
            }
            for (; i + 3 < cn; i += 4) {
                ushort4 e4 = *(const ushort4*)(bk + i);
                uint_t u0 = xu[(size_t)e4.x * 32 + li];
                uint_t u1 = xu[(size_t)e4.y * 32 + li];
                uint_t u2 = xu[(size_t)e4.z * 32 + li];
                uint_t u3 = xu[(size_t)e4.w * 32 + li];
                A0 += bits2f(u0); A1 += bits2f(u0 >> 16);
                B0 += bits2f(u1); B1 += bits2f(u1 >> 16);
                C0 += bits2f(u2); C1 += bits2f(u2 >> 16);
                D0 += bits2f(u3); D1 += bits2f(u3 >> 16);
            }
            for (; i < cn; i++) {
                uint_t u = xu[(size_t)bk[i] * 32 + li];
                s0 += bits2f(u); s1 += bits2f(u >> 16);
            }
            r0 = s0 + ((A0 + B0) + (C0 + D0)) + ((E0 + F0) + (G0 + H0));
            r1 = s1 + ((A1 + B1) + (C1 + D1)) + ((E1 + F1) + (G1 + H1));
        }
        ((uint_t*)&t[g * 8 + j][0])[li] = pack2(r0, r1);
    }
    __syncthreads();
    // ---- MLP phase (mlp1 body, A-fragments from LDS) ----
    int w = tid >> 6;
    int l = tid & 63;
    int q = l >> 4;
    int c = l & 15;
    short8 a0 = *(const short8*)&t[w * 16 + c][q * 8];
    short8 a1 = *(const short8*)&t[w * 16 + c][32 + q * 8];
    __syncthreads();   // a0/a1 in regs before t is overwritten
#pragma unroll
    for (int nt = 0; nt < 8; nt++) {
        float bb = b1[nt * 16 + c];
        f32x4 acc = {bb, bb, bb, bb};
        short8 bf0 = *(const short8*)(pW1 + (size_t)((nt * 2 + 0) * 64 + l) * 8);
        short8 bf1 = *(const short8*)(pW1 + (size_t)((nt * 2 + 1) * 64 + l) * 8);
        acc = __builtin_amdgcn_mfma_f32_16x16x32_bf16(a0, bf0, acc, 0, 0, 0);
        acc = __builtin_amdgcn_mfma_f32_16x16x32_bf16(a1, bf1, acc, 0, 0, 0);
#pragma unroll
        for (int r = 0; r < 4; r++)
            t[w * 16 + q * 4 + r][nt * 16 + c] = f2bits(fmaxf(acc[r], 0.0f));
    }
    __syncthreads();
    short8 A[4];
#pragma unroll
    for (int kc = 0; kc < 4; kc++)
        A[kc] = *(const short8*)&t[w * 16 + c][kc * 32 + q * 8];
#pragma unroll
    for (int nt = 0; nt < 8; nt++) {
        float bb = b2[nt * 16 + c];
        f32x4 acc = {bb, bb, bb, bb};
#pragma unroll
        for (int kc = 0; kc < 4; kc++) {
            short8 bf = *(const short8*)(pW2 + (size_t)((nt * 4 + kc) * 64 + l) * 8);
            acc = __builtin_amdgcn_mfma_f32_16x16x32_bf16(A[kc], bf, acc, 0, 0, 0);
        }
#pragma unroll
        for (int r = 0; r < 4; r++) {
            int rr = m0 + w * 16 + q * 4 + r;
            if (rr < N_NODES)
                h1[(size_t)rr * HIDDEN + nt * 16 + c] = f2bits(fmaxf(acc[r], 0.0f));
        }
    }
}

// layer2 = gather2 (into LDS) + mlp2.  64 nodes/block, 256 threads.
__global__ __launch_bounds__(256) void layer2(const ushort_t* __restrict__ h1,
                                              const int* __restrict__ cnt,
                                              const ushort_t* __restrict__ bucket,
                                              const float* __restrict__ eps2,
                                              const ushort_t* __restrict__ pW3,
                                              const float* __restrict__ b3,
                                              const ushort_t* __restrict__ pW4,
                                              const float* __restrict__ b4,
                                              float* __restrict__ out) {
    __shared__ __align__(16) ushort_t t[64][TPAD];   // 17.4 KB, reused agg -> inter-MLP tile
    int tid = threadIdx.x;
    int m0 = blockIdx.x * 64;
    // ---- gather phase: 4 waves; wave wv does nodes m0+wv*16+j, full 128-ch row ----
    int wv = tid >> 6, lane = tid & 63;
    const uint_t* h1u = (const uint_t*)h1;
    float se = 1.0f + eps2[0];
    for (int j = 0; j < 16; j++) {
        int n = m0 + wv * 16 + j;
        float r0 = 0.f, r1 = 0.f;
        if (n < N_NODES) {
            uint_t v = h1u[(size_t)n * 64 + lane];
            float s0 = se * bits2f(v), s1 = se * bits2f(v >> 16);
            float A0 = 0.f, A1 = 0.f, B0 = 0.f, B1 = 0.f, C0 = 0.f, C1 = 0.f, D0 = 0.f, D1 = 0.f;
            float E0 = 0.f, E1 = 0.f, F0 = 0.f, F1 = 0.f, G0 = 0.f, G1 = 0.f, H0 = 0.f, H1 = 0.f;
            int cn = cnt[n]; if (cn > CAP) cn = CAP;
            const ushort_t* bk = bucket + (size_t)n * CAP;
            int i = 0;
            for (; i + 7 < cn; i += 8) {
                uint4 p = *(const uint4*)(bk + i);
                uint_t u0 = h1u[(size_t)(p.x & 0xFFFFu) * 64 + lane];
                uint_t u1 = h1u[(size_t)(p.x >> 16) * 64 + lane];
                uint_t u2 = h1u[(size_t)(p.y & 0xFFFFu) * 64 + lane];
                uint_t u3 = h1u[(size_t)(p.y >> 16) * 64 + lane];
                uint_t u4 = h1u[(size_t)(p.z & 0xFFFFu) * 64 + lane];
                uint_t u5 = h1u[(size_t)(p.z >> 16) * 64 + lane];
                uint_t u6 = h1u[(size_t)(p.w & 0xFFFFu) * 64 + lane];
                uint_t u7 = h1u[(size_t)(p.w >> 16) * 64 + lane];
                A0 += bits2f(u0); A1 += bits2f(u0 >> 16);
                B0 += bits2f(u1); B1 += bits2f(u1 >> 16);
                C0 += bits2f(u2); C1 += bits2f(u2 >> 16);
                D0 += bits2f(u3); D1 += bits2f(u3 >> 16);
                E0 += bits2f(u4); E1 += bits2f(u4 >> 16);
                F0 += bits2f(u5); F1 += bits2f(u5 >> 16);
                G0 += bits2f(u6); G1 += bits2f(u6 >> 16);
                H0 += bits2f(u7); H1 += bits2f(u7 >> 16);
            }
            for (; i + 3 < cn; i += 4) {
                ushort4 e4 = *(const ushort4*)(bk + i);
                uint_t u0 = h1u[(size_t)e4.x * 64 + lane];
                uint_t u1 = h1u[(size_t)e4.y * 64 + lane];
                uint_t u2 = h1u[(size_t)e4.z * 64 + lane];
                uint_t u3 = h1u[(size_t)e4.w * 64 + lane];
                A0 += bits2f(u0); A1 += bits2f(u0 >> 16);
                B0 += bits2f(u1); B1 += bits2f(u1 >> 16);
                C0 += bits2f(u2); C1 += bits2f(u2 >> 16);
                D0 += bits2f(u3); D1 += bits2f(u3 >> 16);
            }
            for (; i < cn; i++) {
                uint_t u = h1u[(size_t)bk[i] * 64 + lane];
                s0 += bits2f(u); s1 += bits2f(u >> 16);
            }
            r0 = s0 + ((A0 + B0) + (C0 + D0)) + ((E0 + F0) + (G0 + H0));
            r1 = s1 + ((A1 + B1) + (C1 + D1)) + ((E1 + F1) + (G1 + H1));
        }
        ((uint_t*)&t[wv * 16 + j][0])[lane] = pack2(r0, r1);
    }
    __syncthreads();
    // ---- MLP phase (mlp2 body, A-fragments from LDS) ----
    int w = tid >> 6;
    int l = tid & 63;
    int q = l >> 4;
    int c = l & 15;
    short8 A[4];
#pragma unroll
    for (int kc = 0; kc < 4; kc++)
        A[kc] = *(const short8*)&t[w * 16 + c][kc * 32 + q * 8];
    __syncthreads();   // A in regs before t is overwritten
#pragma unroll
    for (int nt = 0; nt < 8; nt++) {
        float bb = b3[nt * 16 + c];
        f32x4 acc = {bb, bb, bb, bb};
#pragma unroll
        for (int kc = 0; kc < 4; kc++) {
            short8 bf = *(const short8*)(pW3 + (size_t)((nt * 4 + kc) * 64 + l) * 8);
            acc = __builtin_amdgcn_mfma_f32_16x16x32_bf16(A[kc], bf, acc, 0, 0, 0);
        }
#pragma unroll
        for (int r = 0; r < 4; r++)
            t[w * 16 + q * 4 + r][nt * 16 + c] = f2bits(fmaxf(acc[r], 0.0f));
    }
    __syncthreads();
    short8 B[4];
#pragma unroll
    for (int kc = 0; kc < 4; kc++)
        B[kc] = *(const short8*)&t[w * 16 + c][kc * 32 + q * 8];
#pragma unroll
    for (int nt = 0; nt < 4; nt++) {
        float bb = b4[nt * 16 + c];
        f32x4 acc = {bb, bb, bb, bb};
#pragma unroll
        for (int kc = 0; kc < 4; kc++) {
            short8 bf = *(const short8*)(pW4 + (size_t)((nt * 4 + kc) * 64 + l) * 8);
            acc = __builtin_amdgcn_mfma_f32_16x16x32_bf16(B[kc], bf, acc, 0, 0, 0);
        }
#pragma unroll
        for (int r = 0; r < 4; r++) {
            int rr = m0 + w * 16 + q * 4 + r;
            if (rr < N_NODES)
                out[(size_t)rr * OUT_CH + nt * 16 + c] = acc[r];
        }
    }
}

extern "C" void kernel_launch(void* const* d_in, const int* in_sizes, int n_in,
                              void* d_out, int out_size, void* d_ws, size_t ws_size,
                              hipStream_t stream) {
    const float* x    = (const float*)d_in[0];
    const int*   ei   = (const int*)d_in[1];
    const float* W1   = (const float*)d_in[2];
    const float* b1   = (const float*)d_in[3];
    const float* W2   = (const float*)d_in[4];
    const float* b2   = (const float*)d_in[5];
    const float* eps1 = (const float*)d_in[6];
    const float* W3   = (const float*)d_in[7];
    const float* b3   = (const float*)d_in[8];
    const float* W4   = (const float*)d_in[9];
    const float* b4   = (const float*)d_in[10];
    const float* eps2 = (const float*)d_in[11];
    float* out = (float*)d_out;

    ushort_t* wsU = (ushort_t*)d_ws;
    uint_t*   xb    = (uint_t*)wsU;                 // 6.4 MB bf16 x
    ushort_t* h1    = wsU + (size_t)6400000;        // 12.8 MB bf16 h1
    ushort_t* pW    = wsU + (size_t)16000000;
    ushort_t* pW1 = pW;              // 8192
    ushort_t* pW2 = pW + 8192;       // 16384
    ushort_t* pW3 = pW + 24576;      // 16384
    ushort_t* pW4 = pW + 40960;      // 8192  (ends at ushort 16049152)
    int* cnt         = (int*)(wsU + (size_t)16049152);
    ushort_t* bucket = (ushort_t*)(cnt + N_NODES);                 // 3.2M ushorts
    int* gcur        = (int*)(bucket + (size_t)N_NODES * CAP);
    uint_t* seg      = (uint_t*)(gcur + 256);                      // 196*4608 uints

    // ---- CSR pass A merged with prep (weight pack + x->bf16) ----
    hipMemsetAsync(gcur, 0, BINS * sizeof(int), stream);
    int cvtBlocks = (N_NODES * IN_CH / 2 + 255) / 256;   // 6250
    binA_prep<<<448 + cvtBlocks, 256, 0, stream>>>(
        ei, gcur, seg, x, xb, W1, pW1, W2, pW2, W3, pW3, W4, pW4);
    binB<<<BINS, 256, 0, stream>>>(seg, gcur, cnt, bucket);

    // ---- fused layers: gather (LDS) + MFMA MLP ----
    layer1<<<(N_NODES + 63) / 64, 256, 0, stream>>>(xb, cnt, bucket, eps1, pW1, b1, pW2, b2, h1);
    layer2<<<(N_NODES + 63) / 64, 256, 0, stream>>>(h1, cnt, bucket, eps2, pW3, b3, pW4, b4, out);
}

// Round 4
// 183.278 us; speedup vs baseline: 1.1368x; 1.1368x over previous
//
#include <hip/hip_runtime.h>

#define N_NODES 50000
#define N_EDGES 800000
#define IN_CH 64
#define HIDDEN 128
#define OUT_CH 64
#define CAP 64      // bucket capacity/node (Binomial(800K,1/50K): P(deg>=64)~2e-18)
#define BINS 196    // nodes/bin = 256
#define CHUNK 3125  // edges per binA block (256 blocks)
#define LCAP 48     // LDS per-bin capacity in binA
#define SEGCAP 4608 // per-bin segment capacity

typedef unsigned short ushort_t;
typedef unsigned int uint_t;
typedef __attribute__((ext_vector_type(8))) short short8;
typedef __attribute__((ext_vector_type(4))) float f32x4;

__device__ __forceinline__ float bits2f(unsigned int u16) {
    union { unsigned int i; float f; } v;
    v.i = (u16 & 0xFFFFu) << 16;
    return v.f;
}

__device__ __forceinline__ ushort_t f2bits(float f) {
    union { float f; unsigned int i; } v;
    v.f = f;
    unsigned int x = v.i;
    if ((x & 0x7F800000u) == 0x7F800000u) return (ushort_t)(x >> 16); // inf/nan
    unsigned int r = (x + 0x7FFFu + ((x >> 16) & 1u)) >> 16;          // RNE
    return (ushort_t)r;
}

__device__ __forceinline__ uint_t pack2(float x, float y) {
    return (uint_t)f2bits(x) | ((uint_t)f2bits(y) << 16);
}

// ===== merged pass: binA (blocks 0..255) + weight pack (256..447) + x cvt ==
__global__ __launch_bounds__(256) void binA_prep(const int* __restrict__ ei,
                                                 int* __restrict__ gcur,
                                                 uint_t* __restrict__ seg,
                                                 const float* __restrict__ x,
                                                 uint_t* __restrict__ xu,
                                                 const float* __restrict__ W1, ushort_t* __restrict__ pW1,
                                                 const float* __restrict__ W2, ushort_t* __restrict__ pW2,
                                                 const float* __restrict__ W3, ushort_t* __restrict__ pW3,
                                                 const float* __restrict__ W4, ushort_t* __restrict__ pW4) {
    __shared__ uint_t lbin[BINS][LCAP];   // 37.6 KB (allocated for all blocks)
    __shared__ int lcnt[BINS];
    __shared__ int lbase[BINS];
    int blk = blockIdx.x;
    int t = threadIdx.x;
    if (blk < 256) {
        // ---------------- binA: LDS-binned edge partition ----------------
        for (int i = t; i < BINS; i += 256) lcnt[i] = 0;
        __syncthreads();
        int e0 = blk * CHUNK;
        int e1 = e0 + CHUNK; if (e1 > N_EDGES) e1 = N_EDGES;
        for (int e = e0 + t; e < e1; e += 256) {
            int src = ei[e];
            int dst = ei[N_EDGES + e];
            int bin = dst >> 8;
            uint_t rec = ((uint_t)src << 16) | (uint_t)(dst & 255);
            int pos = atomicAdd(&lcnt[bin], 1);
            if (pos < LCAP) {
                lbin[bin][pos] = rec;
            } else {
                int gp = atomicAdd(&gcur[bin], 1);
                if (gp < SEGCAP) seg[(size_t)bin * SEGCAP + gp] = rec;
            }
        }
        __syncthreads();
        for (int i = t; i < BINS; i += 256) {
            int c = lcnt[i]; if (c > LCAP) c = LCAP;
            lbase[i] = atomicAdd(&gcur[i], c);
        }
        __syncthreads();
        int wv = t >> 6, ln = t & 63;
        for (int i = wv; i < BINS; i += 4) {
            int c = lcnt[i]; if (c > LCAP) c = LCAP;
            int base = lbase[i];
            for (int j = ln; j < c; j += 64)
                seg[(size_t)i * SEGCAP + base + j] = lbin[i][j];
        }
    } else if (blk < 448) {
        // ---------------- weight pack (fragment order, bf16) -------------
        int b = blk - 256;
        const float* W; ushort_t* o; int K, C, b0;
        if (b < 32)       { W = W1; o = pW1; K = IN_CH;  C = HIDDEN; b0 = 0; }
        else if (b < 96)  { W = W2; o = pW2; K = HIDDEN; C = HIDDEN; b0 = 32; }
        else if (b < 160) { W = W3; o = pW3; K = HIDDEN; C = HIDDEN; b0 = 96; }
        else              { W = W4; o = pW4; K = HIDDEN; C = OUT_CH; b0 = 160; }
        int tid = (b - b0) * 256 + t;
        int j = tid & 7;
        int l = (tid >> 3) & 63;
        int rest = tid >> 9;
        int KC = K >> 5;
        int kc = rest % KC;
        int nt = rest / KC;
        int k = kc * 32 + (l >> 4) * 8 + j;
        int n = nt * 16 + (l & 15);
        o[tid] = f2bits(W[(size_t)k * C + n]);
    } else {
        // ---------------- x -> bf16 convert ------------------------------
        int i = (blk - 448) * 256 + t;
        if (i < N_NODES * IN_CH / 2) {
            float2 v = ((const float2*)x)[i];
            xu[i] = pack2(v.x, v.y);
        }
    }
}

// ============== CSR pass B: per-bin bucket build, coalesced writes =========
__global__ __launch_bounds__(256) void binB(const uint_t* __restrict__ seg,
                                            const int* __restrict__ gcur,
                                            int* __restrict__ cnt,
                                            ushort_t* __restrict__ bucket) {
    __shared__ ushort_t lb[256 * CAP];    // 32 KB
    __shared__ int lc[256];
    int b = blockIdx.x;
    int t = threadIdx.x;
    lc[t] = 0;
    __syncthreads();
    int c = gcur[b]; if (c > SEGCAP) c = SEGCAP;
    const uint_t* s = seg + (size_t)b * SEGCAP;
    for (int i = t; i < c; i += 256) {
        uint_t rec = s[i];
        int ldst = rec & 255;
        int pos = atomicAdd(&lc[ldst], 1);
        if (pos < CAP) lb[ldst * CAP + pos] = (ushort_t)(rec >> 16);
    }
    __syncthreads();
    int n0 = b * 256;
    int nvalid = N_NODES - n0; if (nvalid > 256) nvalid = 256;
    uint4* gb = (uint4*)(bucket + (size_t)n0 * CAP);
    const uint4* lbv = (const uint4*)lb;
    int total = nvalid * (CAP / 8);
    for (int i = t; i < total; i += 256) gb[i] = lbv[i];
    if (t < nvalid) cnt[n0 + t] = lc[t];
}

// ======================= gather aggregations (bf16 out, 16-way ILP) ========
__global__ __launch_bounds__(256) void gather1(const uint_t* __restrict__ xu,
                                               const int* __restrict__ cnt,
                                               const ushort_t* __restrict__ bucket,
                                               const float* __restrict__ eps1,
                                               uint_t* __restrict__ agg1b) {
    int tid = threadIdx.x;
    int li = tid & 31;
    int n = blockIdx.x * 8 + (tid >> 5);
    uint_t v = xu[(size_t)n * 32 + li];
    float se = 1.0f + eps1[0];
    float s0 = se * bits2f(v), s1 = se * bits2f(v >> 16);
    float A0 = 0.f, A1 = 0.f, B0 = 0.f, B1 = 0.f, C0 = 0.f, C1 = 0.f, D0 = 0.f, D1 = 0.f;
    float E0 = 0.f, E1 = 0.f, F0 = 0.f, F1 = 0.f, G0 = 0.f, G1 = 0.f, H0 = 0.f, H1 = 0.f;
    int cn = cnt[n]; if (cn > CAP) cn = CAP;
    const ushort_t* bk = bucket + (size_t)n * CAP;
    int i = 0;
    // 16 outstanding loads; accumulation order identical to two 8-batches.
    for (; i + 15 < cn; i += 16) {
        uint4 p  = *(const uint4*)(bk + i);
        uint4 pp = *(const uint4*)(bk + i + 8);
        uint_t u0 = xu[(size_t)(p.x & 0xFFFFu) * 32 + li];
        uint_t u1 = xu[(size_t)(p.x >> 16) * 32 + li];
        uint_t u2 = xu[(size_t)(p.y & 0xFFFFu) * 32 + li];
        uint_t u3 = xu[(size_t)(p.y >> 16) * 32 + li];
        uint_t u4 = xu[(size_t)(p.z & 0xFFFFu) * 32 + li];
        uint_t u5 = xu[(size_t)(p.z >> 16) * 32 + li];
        uint_t u6 = xu[(size_t)(p.w & 0xFFFFu) * 32 + li];
        uint_t u7 = xu[(size_t)(p.w >> 16) * 32 + li];
        uint_t u8 = xu[(size_t)(pp.x & 0xFFFFu) * 32 + li];
        uint_t u9 = xu[(size_t)(pp.x >> 16) * 32 + li];
        uint_t uA = xu[(size_t)(pp.y & 0xFFFFu) * 32 + li];
        uint_t uB = xu[(size_t)(pp.y >> 16) * 32 + li];
        uint_t uC = xu[(size_t)(pp.z & 0xFFFFu) * 32 + li];
        uint_t uD = xu[(size_t)(pp.z >> 16) * 32 + li];
        uint_t uE = xu[(size_t)(pp.w & 0xFFFFu) * 32 + li];
        uint_t uF = xu[(size_t)(pp.w >> 16) * 32 + li];
        A0 += bits2f(u0); A1 += bits2f(u0 >> 16);
        B0 += bits2f(u1); B1 += bits2f(u1 >> 16);
        C0 += bits2f(u2); C1 += bits2f(u2 >> 16);
        D0 += bits2f(u3); D1 += bits2f(u3 >> 16);
        E0 += bits2f(u4); E1 += bits2f(u4 >> 16);
        F0 += bits2f(u5); F1 += bits2f(u5 >> 16);
        G0 += bits2f(u6); G1 += bits2f(u6 >> 16);
        H0 += bits2f(u7); H1 += bits2f(u7 >> 16);
        A0 += bits2f(u8); A1 += bits2f(u8 >> 16);
        B0 += bits2f(u9); B1 += bits2f(u9 >> 16);
        C0 += bits2f(uA); C1 += bits2f(uA >> 16);
        D0 += bits2f(uB); D1 += bits2f(uB >> 16);
        E0 += bits2f(uC); E1 += bits2f(uC >> 16);
        F0 += bits2f(uD); F1 += bits2f(uD >> 16);
        G0 += bits2f(uE); G1 += bits2f(uE >> 16);
        H0 += bits2f(uF); H1 += bits2f(uF >> 16);
    }
    for (; i + 7 < cn; i += 8) {
        uint4 p = *(const uint4*)(bk + i);
        uint_t u0 = xu[(size_t)(p.x & 0xFFFFu) * 32 + li];
        uint_t u1 = xu[(size_t)(p.x >> 16) * 32 + li];
        uint_t u2 = xu[(size_t)(p.y & 0xFFFFu) * 32 + li];
        uint_t u3 = xu[(size_t)(p.y >> 16) * 32 + li];
        uint_t u4 = xu[(size_t)(p.z & 0xFFFFu) * 32 + li];
        uint_t u5 = xu[(size_t)(p.z >> 16) * 32 + li];
        uint_t u6 = xu[(size_t)(p.w & 0xFFFFu) * 32 + li];
        uint_t u7 = xu[(size_t)(p.w >> 16) * 32 + li];
        A0 += bits2f(u0); A1 += bits2f(u0 >> 16);
        B0 += bits2f(u1); B1 += bits2f(u1 >> 16);
        C0 += bits2f(u2); C1 += bits2f(u2 >> 16);
        D0 += bits2f(u3); D1 += bits2f(u3 >> 16);
        E0 += bits2f(u4); E1 += bits2f(u4 >> 16);
        F0 += bits2f(u5); F1 += bits2f(u5 >> 16);
        G0 += bits2f(u6); G1 += bits2f(u6 >> 16);
        H0 += bits2f(u7); H1 += bits2f(u7 >> 16);
    }
    for (; i + 3 < cn; i += 4) {
        ushort4 e4 = *(const ushort4*)(bk + i);
        uint_t u0 = xu[(size_t)e4.x * 32 + li];
        uint_t u1 = xu[(size_t)e4.y * 32 + li];
        uint_t u2 = xu[(size_t)e4.z * 32 + li];
        uint_t u3 = xu[(size_t)e4.w * 32 + li];
        A0 += bits2f(u0); A1 += bits2f(u0 >> 16);
        B0 += bits2f(u1); B1 += bits2f(u1 >> 16);
        C0 += bits2f(u2); C1 += bits2f(u2 >> 16);
        D0 += bits2f(u3); D1 += bits2f(u3 >> 16);
    }
    for (; i < cn; i++) {
        uint_t u = xu[(size_t)bk[i] * 32 + li];
        s0 += bits2f(u); s1 += bits2f(u >> 16);
    }
    agg1b[(size_t)n * 32 + li] =
        pack2(s0 + ((A0 + B0) + (C0 + D0)) + ((E0 + F0) + (G0 + H0)),
              s1 + ((A1 + B1) + (C1 + D1)) + ((E1 + F1) + (G1 + H1)));
}

__global__ __launch_bounds__(256) void gather2(const ushort_t* __restrict__ h1,
                                               const int* __restrict__ cnt,
                                               const ushort_t* __restrict__ bucket,
                                               const float* __restrict__ eps2,
                                               uint_t* __restrict__ agg2b) {
    int lane = threadIdx.x & 63;
    int n = blockIdx.x * 4 + (threadIdx.x >> 6);
    const uint_t* h1u = (const uint_t*)h1;
    uint_t v = h1u[(size_t)n * 64 + lane];
    float se = 1.0f + eps2[0];
    float s0 = se * bits2f(v), s1 = se * bits2f(v >> 16);
    float A0 = 0.f, A1 = 0.f, B0 = 0.f, B1 = 0.f, C0 = 0.f, C1 = 0.f, D0 = 0.f, D1 = 0.f;
    float E0 = 0.f, E1 = 0.f, F0 = 0.f, F1 = 0.f, G0 = 0.f, G1 = 0.f, H0 = 0.f, H1 = 0.f;
    int cn = cnt[n]; if (cn > CAP) cn = CAP;
    const ushort_t* bk = bucket + (size_t)n * CAP;
    int i = 0;
    // 16 outstanding loads; accumulation order identical to two 8-batches.
    for (; i + 15 < cn; i += 16) {
        uint4 p  = *(const uint4*)(bk + i);
        uint4 pp = *(const uint4*)(bk + i + 8);
        uint_t u0 = h1u[(size_t)(p.x & 0xFFFFu) * 64 + lane];
        uint_t u1 = h1u[(size_t)(p.x >> 16) * 64 + lane];
        uint_t u2 = h1u[(size_t)(p.y & 0xFFFFu) * 64 + lane];
        uint_t u3 = h1u[(size_t)(p.y >> 16) * 64 + lane];
        uint_t u4 = h1u[(size_t)(p.z & 0xFFFFu) * 64 + lane];
        uint_t u5 = h1u[(size_t)(p.z >> 16) * 64 + lane];
        uint_t u6 = h1u[(size_t)(p.w & 0xFFFFu) * 64 + lane];
        uint_t u7 = h1u[(size_t)(p.w >> 16) * 64 + lane];
        uint_t u8 = h1u[(size_t)(pp.x & 0xFFFFu) * 64 + lane];
        uint_t u9 = h1u[(size_t)(pp.x >> 16) * 64 + lane];
        uint_t uA = h1u[(size_t)(pp.y & 0xFFFFu) * 64 + lane];
        uint_t uB = h1u[(size_t)(pp.y >> 16) * 64 + lane];
        uint_t uC = h1u[(size_t)(pp.z & 0xFFFFu) * 64 + lane];
        uint_t uD = h1u[(size_t)(pp.z >> 16) * 64 + lane];
        uint_t uE = h1u[(size_t)(pp.w & 0xFFFFu) * 64 + lane];
        uint_t uF = h1u[(size_t)(pp.w >> 16) * 64 + lane];
        A0 += bits2f(u0); A1 += bits2f(u0 >> 16);
        B0 += bits2f(u1); B1 += bits2f(u1 >> 16);
        C0 += bits2f(u2); C1 += bits2f(u2 >> 16);
        D0 += bits2f(u3); D1 += bits2f(u3 >> 16);
        E0 += bits2f(u4); E1 += bits2f(u4 >> 16);
        F0 += bits2f(u5); F1 += bits2f(u5 >> 16);
        G0 += bits2f(u6); G1 += bits2f(u6 >> 16);
        H0 += bits2f(u7); H1 += bits2f(u7 >> 16);
        A0 += bits2f(u8); A1 += bits2f(u8 >> 16);
        B0 += bits2f(u9); B1 += bits2f(u9 >> 16);
        C0 += bits2f(uA); C1 += bits2f(uA >> 16);
        D0 += bits2f(uB); D1 += bits2f(uB >> 16);
        E0 += bits2f(uC); E1 += bits2f(uC >> 16);
        F0 += bits2f(uD); F1 += bits2f(uD >> 16);
        G0 += bits2f(uE); G1 += bits2f(uE >> 16);
        H0 += bits2f(uF); H1 += bits2f(uF >> 16);
    }
    for (; i + 7 < cn; i += 8) {
        uint4 p = *(const uint4*)(bk + i);
        uint_t u0 = h1u[(size_t)(p.x & 0xFFFFu) * 64 + lane];
        uint_t u1 = h1u[(size_t)(p.x >> 16) * 64 + lane];
        uint_t u2 = h1u[(size_t)(p.y & 0xFFFFu) * 64 + lane];
        uint_t u3 = h1u[(size_t)(p.y >> 16) * 64 + lane];
        uint_t u4 = h1u[(size_t)(p.z & 0xFFFFu) * 64 + lane];
        uint_t u5 = h1u[(size_t)(p.z >> 16) * 64 + lane];
        uint_t u6 = h1u[(size_t)(p.w & 0xFFFFu) * 64 + lane];
        uint_t u7 = h1u[(size_t)(p.w >> 16) * 64 + lane];
        A0 += bits2f(u0); A1 += bits2f(u0 >> 16);
        B0 += bits2f(u1); B1 += bits2f(u1 >> 16);
        C0 += bits2f(u2); C1 += bits2f(u2 >> 16);
        D0 += bits2f(u3); D1 += bits2f(u3 >> 16);
        E0 += bits2f(u4); E1 += bits2f(u4 >> 16);
        F0 += bits2f(u5); F1 += bits2f(u5 >> 16);
        G0 += bits2f(u6); G1 += bits2f(u6 >> 16);
        H0 += bits2f(u7); H1 += bits2f(u7 >> 16);
    }
    for (; i + 3 < cn; i += 4) {
        ushort4 e4 = *(const ushort4*)(bk + i);
        uint_t u0 = h1u[(size_t)e4.x * 64 + lane];
        uint_t u1 = h1u[(size_t)e4.y * 64 + lane];
        uint_t u2 = h1u[(size_t)e4.z * 64 + lane];
        uint_t u3 = h1u[(size_t)e4.w * 64 + lane];
        A0 += bits2f(u0); A1 += bits2f(u0 >> 16);
        B0 += bits2f(u1); B1 += bits2f(u1 >> 16);
        C0 += bits2f(u2); C1 += bits2f(u2 >> 16);
        D0 += bits2f(u3); D1 += bits2f(u3 >> 16);
    }
    for (; i < cn; i++) {
        uint_t u = h1u[(size_t)bk[i] * 64 + lane];
        s0 += bits2f(u); s1 += bits2f(u >> 16);
    }
    agg2b[(size_t)n * 64 + lane] =
        pack2(s0 + ((A0 + B0) + (C0 + D0)) + ((E0 + F0) + (G0 + H0)),
              s1 + ((A1 + B1) + (C1 + D1)) + ((E1 + F1) + (G1 + H1)));
}

// ======================= MFMA MLPs =======================
// mfma_f32_16x16x32_bf16 layouts (m89/m91/m120-verified):
//   A: lane l holds A[m=l&15][k=(l>>4)*8+j];  B: lane l holds B[k=(l>>4)*8+j][n=l&15]
//   D: lane l, reg r holds D[(l>>4)*4+r][l&15]
#define TPAD 136   // LDS row stride in ushorts

__global__ __launch_bounds__(256) void mlp1(const ushort_t* __restrict__ agg1b,
                                            const ushort_t* __restrict__ pW1,
                                            const float* __restrict__ b1,
                                            const ushort_t* __restrict__ pW2,
                                            const float* __restrict__ b2,
                                            ushort_t* __restrict__ h1) {
    __shared__ __align__(16) ushort_t t[64][TPAD];
    int w = threadIdx.x >> 6;
    int l = threadIdx.x & 63;
    int q = l >> 4;
    int c = l & 15;
    int m0 = blockIdx.x * 64 + w * 16;
    int node = m0 + c;
    int nc = node < N_NODES ? node : 0;
    short8 a0 = *(const short8*)(agg1b + (size_t)nc * IN_CH + q * 8);
    short8 a1 = *(const short8*)(agg1b + (size_t)nc * IN_CH + 32 + q * 8);
#pragma unroll
    for (int nt = 0; nt < 8; nt++) {
        float bb = b1[nt * 16 + c];
        f32x4 acc = {bb, bb, bb, bb};
        short8 bf0 = *(const short8*)(pW1 + (size_t)((nt * 2 + 0) * 64 + l) * 8);
        short8 bf1 = *(const short8*)(pW1 + (size_t)((nt * 2 + 1) * 64 + l) * 8);
        acc = __builtin_amdgcn_mfma_f32_16x16x32_bf16(a0, bf0, acc, 0, 0, 0);
        acc = __builtin_amdgcn_mfma_f32_16x16x32_bf16(a1, bf1, acc, 0, 0, 0);
#pragma unroll
        for (int r = 0; r < 4; r++)
            t[w * 16 + q * 4 + r][nt * 16 + c] = f2bits(fmaxf(acc[r], 0.0f));
    }
    __syncthreads();
    short8 A[4];
#pragma unroll
    for (int kc = 0; kc < 4; kc++)
        A[kc] = *(const short8*)&t[w * 16 + c][kc * 32 + q * 8];
#pragma unroll
    for (int nt = 0; nt < 8; nt++) {
        float bb = b2[nt * 16 + c];
        f32x4 acc = {bb, bb, bb, bb};
#pragma unroll
        for (int kc = 0; kc < 4; kc++) {
            short8 bf = *(const short8*)(pW2 + (size_t)((nt * 4 + kc) * 64 + l) * 8);
            acc = __builtin_amdgcn_mfma_f32_16x16x32_bf16(A[kc], bf, acc, 0, 0, 0);
        }
#pragma unroll
        for (int r = 0; r < 4; r++) {
            int rr = m0 + q * 4 + r;
            if (rr < N_NODES)
                h1[(size_t)rr * HIDDEN + nt * 16 + c] = f2bits(fmaxf(acc[r], 0.0f));
        }
    }
}

__global__ __launch_bounds__(256) void mlp2(const ushort_t* __restrict__ agg2b,
                                            const ushort_t* __restrict__ pW3,
                                            const float* __restrict__ b3,
                                            const ushort_t* __restrict__ pW4,
                                            const float* __restrict__ b4,
                                            float* __restrict__ out) {
    __shared__ __align__(16) ushort_t t[64][TPAD];
    int w = threadIdx.x >> 6;
    int l = threadIdx.x & 63;
    int q = l >> 4;
    int c = l & 15;
    int m0 = blockIdx.x * 64 + w * 16;
    int node = m0 + c;
    int nc = node < N_NODES ? node : 0;
    short8 A[4];
#pragma unroll
    for (int kc = 0; kc < 4; kc++)
        A[kc] = *(const short8*)(agg2b + (size_t)nc * HIDDEN + kc * 32 + q * 8);
#pragma unroll
    for (int nt = 0; nt < 8; nt++) {
        float bb = b3[nt * 16 + c];
        f32x4 acc = {bb, bb, bb, bb};
#pragma unroll
        for (int kc = 0; kc < 4; kc++) {
            short8 bf = *(const short8*)(pW3 + (size_t)((nt * 4 + kc) * 64 + l) * 8);
            acc = __builtin_amdgcn_mfma_f32_16x16x32_bf16(A[kc], bf, acc, 0, 0, 0);
        }
#pragma unroll
        for (int r = 0; r < 4; r++)
            t[w * 16 + q * 4 + r][nt * 16 + c] = f2bits(fmaxf(acc[r], 0.0f));
    }
    __syncthreads();
    short8 B[4];
#pragma unroll
    for (int kc = 0; kc < 4; kc++)
        B[kc] = *(const short8*)&t[w * 16 + c][kc * 32 + q * 8];
#pragma unroll
    for (int nt = 0; nt < 4; nt++) {
        float bb = b4[nt * 16 + c];
        f32x4 acc = {bb, bb, bb, bb};
#pragma unroll
        for (int kc = 0; kc < 4; kc++) {
            short8 bf = *(const short8*)(pW4 + (size_t)((nt * 4 + kc) * 64 + l) * 8);
            acc = __builtin_amdgcn_mfma_f32_16x16x32_bf16(B[kc], bf, acc, 0, 0, 0);
        }
#pragma unroll
        for (int r = 0; r < 4; r++) {
            int rr = m0 + q * 4 + r;
            if (rr < N_NODES)
                out[(size_t)rr * OUT_CH + nt * 16 + c] = acc[r];
        }
    }
}

extern "C" void kernel_launch(void* const* d_in, const int* in_sizes, int n_in,
                              void* d_out, int out_size, void* d_ws, size_t ws_size,
                              hipStream_t stream) {
    const float* x    = (const float*)d_in[0];
    const int*   ei   = (const int*)d_in[1];
    const float* W1   = (const float*)d_in[2];
    const float* b1   = (const float*)d_in[3];
    const float* W2   = (const float*)d_in[4];
    const float* b2   = (const float*)d_in[5];
    const float* eps1 = (const float*)d_in[6];
    const float* W3   = (const float*)d_in[7];
    const float* b3   = (const float*)d_in[8];
    const float* W4   = (const float*)d_in[9];
    const float* b4   = (const float*)d_in[10];
    const float* eps2 = (const float*)d_in[11];
    float* out = (float*)d_out;

    ushort_t* wsU = (ushort_t*)d_ws;
    ushort_t* agg2b = wsU;
    uint_t*   xb    = (uint_t*)wsU;                 // alias, dead before gather2
    ushort_t* h1    = wsU + (size_t)6400000;
    ushort_t* agg1b = wsU + (size_t)12800000;
    ushort_t* pW    = wsU + (size_t)16000000;
    ushort_t* pW1 = pW;              // 8192
    ushort_t* pW2 = pW + 8192;       // 16384
    ushort_t* pW3 = pW + 24576;      // 16384
    ushort_t* pW4 = pW + 40960;      // 8192  (ends at ushort 16049152)
    int* cnt         = (int*)(wsU + (size_t)16049152);
    ushort_t* bucket = (ushort_t*)(cnt + N_NODES);                 // 3.2M ushorts
    int* gcur        = (int*)(bucket + (size_t)N_NODES * CAP);
    uint_t* seg      = (uint_t*)(gcur + 256);                      // 196*4608 uints

    // ---- CSR pass A merged with prep (weight pack + x->bf16) ----
    hipMemsetAsync(gcur, 0, BINS * sizeof(int), stream);
    int cvtBlocks = (N_NODES * IN_CH / 2 + 255) / 256;   // 6250
    binA_prep<<<448 + cvtBlocks, 256, 0, stream>>>(
        ei, gcur, seg, x, xb, W1, pW1, W2, pW2, W3, pW3, W4, pW4);
    binB<<<BINS, 256, 0, stream>>>(seg, gcur, cnt, bucket);

    // ---- layer 1 ----
    gather1<<<N_NODES / 8, 256, 0, stream>>>(xb, cnt, bucket, eps1, (uint_t*)agg1b);
    mlp1<<<(N_NODES + 63) / 64, 256, 0, stream>>>(agg1b, pW1, b1, pW2, b2, h1);

    // ---- layer 2 ---- (gather2 overwrites xb region — xb is dead by now)
    gather2<<<N_NODES / 4, 256, 0, stream>>>(h1, cnt, bucket, eps2, (uint_t*)agg2b);
    mlp2<<<(N_NODES + 63) / 64, 256, 0, stream>>>(agg2b, pW3, b3, pW4, b4, out);
}